// Round 1
// baseline (373.078 us; speedup 1.0000x reference)
//
#include <hip/hip_runtime.h>
#include <hip/hip_bf16.h>

#define B_  8192
#define H_  128
#define F_  128
#define G_  1100
#define NW  1106    // G + 3*W
#define NC  640     // wide gemm output cols (r,u,s,gi_n,gh_n)
#define KK  256     // K for both GEMMs

__device__ __forceinline__ float sigmf(float x) { return 1.0f / (1.0f + expf(-x)); }

// ---------------------------------------------------------------------------
// Prep: build Z = [x | hx] (B x 256), Wbig (640 x 256), init winner = -1
// Wbig rows: [0,128)=r gate (wih|whh), [128,256)=u gate, [256,384)=s gate
// (w rows 384..512), [384,512)=gi_n (wih_n|0), [512,640)=gh_n (0|whh_n)
// ---------------------------------------------------------------------------
__global__ void prep_kernel(const float* __restrict__ xf, const float* __restrict__ hx,
                            const float* __restrict__ w_ih, const float* __restrict__ w_hh,
                            float* __restrict__ Z, float* __restrict__ Wbig,
                            int* __restrict__ winner) {
    size_t stride = (size_t)gridDim.x * blockDim.x;
    size_t id0 = (size_t)blockIdx.x * blockDim.x + threadIdx.x;
    for (size_t i = id0; i < (size_t)B_ * 256; i += stride) {
        size_t b = i >> 8; int c = (int)(i & 255);
        Z[i] = (c < 128) ? xf[b * 128 + c] : hx[b * 128 + (c - 128)];
    }
    for (size_t i = id0; i < (size_t)NC * 256; i += stride) {
        int j = (int)(i >> 8); int k = (int)(i & 255);
        float v;
        if (j < 256) {                       // gates r (0:128) and u (128:256)
            v = (k < 128) ? w_ih[j * 128 + k] : w_hh[j * 128 + (k - 128)];
        } else if (j < 384) {                // gate s -> w rows 384..512
            int r = 384 + (j - 256);
            v = (k < 128) ? w_ih[r * 128 + k] : w_hh[r * 128 + (k - 128)];
        } else if (j < 512) {                // gi_n
            int r = 256 + (j - 384);
            v = (k < 128) ? w_ih[r * 128 + k] : 0.0f;
        } else {                             // gh_n
            int r = 256 + (j - 512);
            v = (k < 128) ? 0.0f : w_hh[r * 128 + (k - 128)];
        }
        Wbig[i] = v;
    }
    for (size_t i = id0; i < (size_t)NW * NW; i += stride) winner[i] = -1;
}

// ---------------------------------------------------------------------------
// Tiled f32 GEMM: C[m][n0+n] = sum_k A[m][k] * Bw[n0+n][k];  K = 256 fixed.
// BM=64, BN=128, KC=32, 256 threads, 4x8 micro-tile per thread.
// ---------------------------------------------------------------------------
__global__ __launch_bounds__(256) void gemm_abt(const float* __restrict__ A,
                                                const float* __restrict__ Bw,
                                                float* __restrict__ Cc, int ldc) {
    __shared__ float As[64][36];    // [row][k] padded: read banks spread, f4-aligned writes
    __shared__ float Ws[32][132];   // [k][col] padded
    int tid = threadIdx.x;
    int tn = tid & 15, tm = tid >> 4;
    size_t m0 = (size_t)blockIdx.x * 64;
    int n0 = blockIdx.y * 128;
    float acc[4][8];
#pragma unroll
    for (int i = 0; i < 4; ++i)
#pragma unroll
        for (int j = 0; j < 8; ++j) acc[i][j] = 0.0f;

    for (int k0 = 0; k0 < KK; k0 += 32) {
        __syncthreads();
#pragma unroll
        for (int p = 0; p < 2; ++p) {       // stage A tile 64x32
            int f = tid + 256 * p; int r = f >> 3, cq = f & 7;
            float4 v = *(const float4*)(A + (m0 + r) * KK + (k0 + 4 * cq));
            *(float4*)(&As[r][4 * cq]) = v;
        }
#pragma unroll
        for (int p = 0; p < 4; ++p) {       // stage Bw tile 128x32 transposed
            int f = tid + 256 * p; int c = f >> 3, cq = f & 7;
            float4 v = *(const float4*)(Bw + (size_t)(n0 + c) * KK + (k0 + 4 * cq));
            Ws[4 * cq + 0][c] = v.x; Ws[4 * cq + 1][c] = v.y;
            Ws[4 * cq + 2][c] = v.z; Ws[4 * cq + 3][c] = v.w;
        }
        __syncthreads();
#pragma unroll
        for (int kk = 0; kk < 32; ++kk) {
            float4 w0 = *(const float4*)(&Ws[kk][4 * tn]);
            float4 w1 = *(const float4*)(&Ws[kk][64 + 4 * tn]);
#pragma unroll
            for (int i = 0; i < 4; ++i) {
                float a = As[4 * tm + i][kk];
                acc[i][0] += a * w0.x; acc[i][1] += a * w0.y;
                acc[i][2] += a * w0.z; acc[i][3] += a * w0.w;
                acc[i][4] += a * w1.x; acc[i][5] += a * w1.y;
                acc[i][6] += a * w1.z; acc[i][7] += a * w1.w;
            }
        }
    }
#pragma unroll
    for (int i = 0; i < 4; ++i) {
        size_t row = m0 + 4 * tm + i;
        float4 v0 = make_float4(acc[i][0], acc[i][1], acc[i][2], acc[i][3]);
        float4 v1 = make_float4(acc[i][4], acc[i][5], acc[i][6], acc[i][7]);
        *(float4*)(Cc + row * ldc + n0 + 4 * tn) = v0;
        *(float4*)(Cc + row * ldc + n0 + 64 + 4 * tn) = v1;
    }
}

// ---------------------------------------------------------------------------
// Attention: one wave per b. Gates from Cbuf, gather 25 rows, softmax, mix.
// Writes mixq=[mix|q], ug, sg; atomicMax winner.
// ---------------------------------------------------------------------------
__global__ __launch_bounds__(64) void attn_kernel(
    const float* __restrict__ C, const float* __restrict__ memory,
    const int* __restrict__ gidx, const float* __restrict__ b_ih,
    const float* __restrict__ b_hh, float* __restrict__ mixq,
    float* __restrict__ ug, float* __restrict__ sg, int* __restrict__ winner) {
    int b = blockIdx.x;
    int t = threadIdx.x;           // 0..63
    int t1 = t + 64;
    const float* Crow = C + (size_t)b * NC;
    float r0 = sigmf(Crow[t]        + b_ih[t]        + b_hh[t]);
    float r1 = sigmf(Crow[t1]       + b_ih[t1]       + b_hh[t1]);
    float u0 = sigmf(Crow[128 + t]  + b_ih[128 + t]  + b_hh[128 + t]);
    float u1 = sigmf(Crow[128 + t1] + b_ih[128 + t1] + b_hh[128 + t1]);
    float s0 = sigmf(Crow[256 + t]  + b_ih[384 + t]  + b_hh[384 + t]);
    float s1 = sigmf(Crow[256 + t1] + b_ih[384 + t1] + b_hh[384 + t1]);
    float n0 = tanhf(Crow[384 + t]  + b_ih[256 + t]  + r0 * (Crow[512 + t]  + b_hh[256 + t]));
    float n1 = tanhf(Crow[384 + t1] + b_ih[256 + t1] + r1 * (Crow[512 + t1] + b_hh[256 + t1]));

    int gx = gidx[2 * b] + 2, gy = gidx[2 * b + 1] + 2;
    const float* base = memory + ((size_t)gx * NW + gy) * H_ + t;
    float cs0[25], cs1[25];
#pragma unroll
    for (int l = 0; l < 25; ++l) {
        int dx = l / 5 - 2, dy = l % 5 - 2;
        const float* row = base + ((long)dx * NW + dy) * H_;
        cs0[l] = row[0];
        cs1[l] = row[64];
    }
    float sc[25];
#pragma unroll
    for (int l = 0; l < 25; ++l) {
        float p = n0 * cs0[l] + n1 * cs1[l];
#pragma unroll
        for (int w = 1; w < 64; w <<= 1) p += __shfl_xor(p, w, 64);
        sc[l] = p;
    }
    float mx = sc[0];
#pragma unroll
    for (int l = 1; l < 25; ++l) mx = fmaxf(mx, sc[l]);
    float den = 0.0f, mix0 = 0.0f, mix1 = 0.0f;
#pragma unroll
    for (int l = 0; l < 25; ++l) {
        float e = expf(sc[l] - mx);
        den += e;
        mix0 += e * cs0[l];
        mix1 += e * cs1[l];
    }
    float inv = 1.0f / den;
    mix0 *= inv; mix1 *= inv;

    float* mq = mixq + (size_t)b * 256;
    mq[t] = mix0; mq[t1] = mix1; mq[128 + t] = n0; mq[128 + t1] = n1;
    ug[(size_t)b * H_ + t] = u0; ug[(size_t)b * H_ + t1] = u1;
    sg[(size_t)b * H_ + t] = s0; sg[(size_t)b * H_ + t1] = s1;
    if (t == 0) atomicMax(&winner[gx * NW + gy], b);
}

// ---------------------------------------------------------------------------
// Bulk copy memory -> new_memory (float4 grid-stride)
// ---------------------------------------------------------------------------
__global__ void copy_kernel(const float4* __restrict__ src, float4* __restrict__ dst, size_t n4) {
    size_t stride = (size_t)gridDim.x * blockDim.x;
    for (size_t i = (size_t)blockIdx.x * blockDim.x + threadIdx.x; i < n4; i += stride)
        dst[i] = src[i];
}

// ---------------------------------------------------------------------------
// Final: atten_cs, curr_state, hyy; scatter winner rows into new_memory
// ---------------------------------------------------------------------------
__global__ __launch_bounds__(128) void final_kernel(
    const float* __restrict__ AC, const float* __restrict__ b_out,
    const float* __restrict__ sg, const float* __restrict__ ug,
    const float* __restrict__ mixq, const float* __restrict__ hx,
    const float* __restrict__ memory, const int* __restrict__ gidx,
    const int* __restrict__ winner, float* __restrict__ hyy,
    float* __restrict__ newmem) {
    int b = blockIdx.x, t = threadIdx.x;
    float atten = tanhf(AC[(size_t)b * H_ + t] + b_out[t]);
    float s = sg[(size_t)b * H_ + t], u = ug[(size_t)b * H_ + t];
    float q = mixq[(size_t)b * 256 + 128 + t];
    float curr = q + s * atten;
    float h = hx[(size_t)b * H_ + t];
    float hy = curr + u * (h - curr);
    hyy[(size_t)b * H_ + t] = hy;
    int gx = gidx[2 * b] + 2, gy = gidx[2 * b + 1] + 2;
    size_t cell = (size_t)gx * NW + gy;
    if (winner[cell] == b) {
        float m = memory[cell * H_ + t];
        newmem[cell * H_ + t] = s * m + (1.0f - s) * hy;
    }
}

extern "C" void kernel_launch(void* const* d_in, const int* in_sizes, int n_in,
                              void* d_out, int out_size, void* d_ws, size_t ws_size,
                              hipStream_t stream) {
    const float* xf     = (const float*)d_in[0];
    const float* hx     = (const float*)d_in[1];
    const int*   gidx   = (const int*)d_in[2];
    const float* memory = (const float*)d_in[3];
    const float* w_ih   = (const float*)d_in[4];
    const float* w_hh   = (const float*)d_in[5];
    const float* b_ih   = (const float*)d_in[6];
    const float* b_hh   = (const float*)d_in[7];
    const float* w_out  = (const float*)d_in[8];
    const float* b_out  = (const float*)d_in[9];

    float* out    = (float*)d_out;
    float* hyy    = out;
    float* newmem = out + (size_t)B_ * H_;

    // Persistent scratch (must survive the bulk copy): mixq, ug, sg, AC, winner
    float* wsf    = (float*)d_ws;
    float* mixq   = wsf;                        // B*256
    float* ug     = mixq + (size_t)B_ * 256;    // B*128
    float* sg     = ug + (size_t)B_ * H_;       // B*128
    float* AC     = sg + (size_t)B_ * H_;       // B*128
    int*   winner = (int*)(AC + (size_t)B_ * H_);   // NW*NW ints
    char*  pers_end = (char*)(winner + (size_t)NW * NW);
    size_t pers_bytes = (size_t)(pers_end - (char*)d_ws);

    // Transient scratch: Z (B*256), Cbuf (B*640), Wbig (640*256)
    size_t ZF = (size_t)B_ * 256, CF = (size_t)B_ * NC, WBF = (size_t)NC * 256;
    size_t trans_bytes = (ZF + CF + WBF) * sizeof(float);
    float* trans;
    if (ws_size >= pers_bytes + trans_bytes) {
        trans = (float*)pers_end;               // all in ws
    } else {
        trans = newmem;                         // stage in not-yet-copied output region
    }
    float* Z    = trans;
    float* Cbuf = Z + ZF;
    float* Wbig = Cbuf + CF;

    // 1. prep: Z, Wbig, winner=-1
    prep_kernel<<<2048, 256, 0, stream>>>(xf, hx, w_ih, w_hh, Z, Wbig, winner);
    // 2. gates pre-activations: Cbuf = Z @ Wbig^T   (8192 x 640)
    gemm_abt<<<dim3(B_ / 64, NC / 128), 256, 0, stream>>>(Z, Wbig, Cbuf, NC);
    // 3. gates + attention: mixq, ug, sg, winner
    attn_kernel<<<B_, 64, 0, stream>>>(Cbuf, memory, gidx, b_ih, b_hh, mixq, ug, sg, winner);
    // 4. AC = mixq @ w_out^T   (8192 x 128)
    gemm_abt<<<dim3(B_ / 64, 1), 256, 0, stream>>>(mixq, w_out, AC, H_);
    // 5. bulk copy memory -> new_memory
    copy_kernel<<<2048, 256, 0, stream>>>((const float4*)memory, (float4*)newmem,
                                          (size_t)NW * NW * H_ / 4);
    // 6. hyy + scatter updates (last-index-wins via winner)
    final_kernel<<<B_, H_, 0, stream>>>(AC, b_out, sg, ug, mixq, hx, memory, gidx,
                                        winner, hyy, newmem);
}

// Round 2
// 281.937 us; speedup vs baseline: 1.3233x; 1.3233x over previous
//
#include <hip/hip_runtime.h>
#include <hip/hip_bf16.h>

typedef float f32x4 __attribute__((ext_vector_type(4)));

#define B_  8192
#define H_  128
#define NW  1106    // G + 3*W
#define NC  640     // wide gemm output cols (r,u,s,gi_n,gh_n)
#define KK  256     // K for both GEMMs

static const size_t N4TOT = (size_t)NW * NW * H_ / 4;   // 39,143,552 float4s

// copy-slice sizes (float4 units) per phase
#define SL_A 2000000UL
#define SL_B 6000000UL
#define SL_C 5000000UL
#define SL_D 2000000UL

#define PREP_CB  512     // prep compute blocks
#define PREP_CPB 768     // prep copy blocks
#define GEMM_CPB 1024
#define ATTN_CPB 4096
#define FIN_BLKS 2048

__device__ __forceinline__ float sigmf(float x) { return 1.0f / (1.0f + expf(-x)); }

__device__ __forceinline__ void copy_span(const f32x4* __restrict__ src,
                                          f32x4* __restrict__ dst,
                                          size_t lo, size_t hi,
                                          size_t ctid, size_t cthreads) {
    for (size_t i = lo + ctid; i < hi; i += cthreads) {
        f32x4 v = __builtin_nontemporal_load(src + i);
        __builtin_nontemporal_store(v, dst + i);
    }
}

// ---------------------------------------------------------------------------
// Prep: Z = [x|hx] (B x 256), Wbig (640 x 256), winner = -1; + copy slice A
// ---------------------------------------------------------------------------
__global__ __launch_bounds__(256) void prep_kernel(
    const float* __restrict__ xf, const float* __restrict__ hx,
    const float* __restrict__ w_ih, const float* __restrict__ w_hh,
    float* __restrict__ Z, float* __restrict__ Wbig, int* __restrict__ winner,
    const f32x4* __restrict__ src, f32x4* __restrict__ dst, size_t lo, size_t hi) {
    int bid = blockIdx.x, tid = threadIdx.x;
    if (bid >= PREP_CB) {
        size_t ctid = (size_t)(bid - PREP_CB) * 256 + tid;
        copy_span(src, dst, lo, hi, ctid, (size_t)(gridDim.x - PREP_CB) * 256);
        return;
    }
    size_t stride = (size_t)PREP_CB * 256;
    size_t id0 = (size_t)bid * 256 + tid;
    for (size_t i = id0; i < (size_t)B_ * 256; i += stride) {
        size_t b = i >> 8; int c = (int)(i & 255);
        Z[i] = (c < 128) ? xf[b * 128 + c] : hx[b * 128 + (c - 128)];
    }
    for (size_t i = id0; i < (size_t)NC * 256; i += stride) {
        int j = (int)(i >> 8); int k = (int)(i & 255);
        float v;
        if (j < 256) {
            v = (k < 128) ? w_ih[j * 128 + k] : w_hh[j * 128 + (k - 128)];
        } else if (j < 384) {
            int r = 384 + (j - 256);
            v = (k < 128) ? w_ih[r * 128 + k] : w_hh[r * 128 + (k - 128)];
        } else if (j < 512) {
            int r = 256 + (j - 384);
            v = (k < 128) ? w_ih[r * 128 + k] : 0.0f;
        } else {
            int r = 256 + (j - 512);
            v = (k < 128) ? 0.0f : w_hh[r * 128 + (k - 128)];
        }
        Wbig[i] = v;
    }
    for (size_t i = id0; i < (size_t)NW * NW; i += stride) winner[i] = -1;
}

// ---------------------------------------------------------------------------
// Tiled f32 GEMM (+ optional atomicMax side-work + copy slice in extra blocks)
// ---------------------------------------------------------------------------
__global__ __launch_bounds__(256) void gemm_abt(
    const float* __restrict__ A, const float* __restrict__ Bw,
    float* __restrict__ Cc, int ldc, int nx, int nxny,
    const int* __restrict__ gidx, int* __restrict__ winner,
    const f32x4* __restrict__ src, f32x4* __restrict__ dst, size_t lo, size_t hi) {
    __shared__ float As[64][36];
    __shared__ float Ws[32][132];
    int bid = blockIdx.x, tid = threadIdx.x;
    if (bid >= nxny) {
        int rel = bid - nxny;
        if (gidx != nullptr && rel < 32) {   // winner atomics (winner init'd in prep)
            int b = rel * 256 + tid;
            int gx = gidx[2 * b] + 2, gy = gidx[2 * b + 1] + 2;
            atomicMax(&winner[gx * NW + gy], b);
        }
        size_t ctid = (size_t)rel * 256 + tid;
        copy_span(src, dst, lo, hi, ctid, (size_t)(gridDim.x - nxny) * 256);
        return;
    }
    int bx = bid % nx, by = bid / nx;
    int tn = tid & 15, tm = tid >> 4;
    size_t m0 = (size_t)bx * 64;
    int n0 = by * 128;
    float acc[4][8];
#pragma unroll
    for (int i = 0; i < 4; ++i)
#pragma unroll
        for (int j = 0; j < 8; ++j) acc[i][j] = 0.0f;

    for (int k0 = 0; k0 < KK; k0 += 32) {
        __syncthreads();
#pragma unroll
        for (int p = 0; p < 2; ++p) {
            int f = tid + 256 * p; int r = f >> 3, cq = f & 7;
            float4 v = *(const float4*)(A + (m0 + r) * KK + (k0 + 4 * cq));
            *(float4*)(&As[r][4 * cq]) = v;
        }
#pragma unroll
        for (int p = 0; p < 4; ++p) {
            int f = tid + 256 * p; int c = f >> 3, cq = f & 7;
            float4 v = *(const float4*)(Bw + (size_t)(n0 + c) * KK + (k0 + 4 * cq));
            Ws[4 * cq + 0][c] = v.x; Ws[4 * cq + 1][c] = v.y;
            Ws[4 * cq + 2][c] = v.z; Ws[4 * cq + 3][c] = v.w;
        }
        __syncthreads();
#pragma unroll
        for (int kk = 0; kk < 32; ++kk) {
            float4 w0 = *(const float4*)(&Ws[kk][4 * tn]);
            float4 w1 = *(const float4*)(&Ws[kk][64 + 4 * tn]);
#pragma unroll
            for (int i = 0; i < 4; ++i) {
                float a = As[4 * tm + i][kk];
                acc[i][0] += a * w0.x; acc[i][1] += a * w0.y;
                acc[i][2] += a * w0.z; acc[i][3] += a * w0.w;
                acc[i][4] += a * w1.x; acc[i][5] += a * w1.y;
                acc[i][6] += a * w1.z; acc[i][7] += a * w1.w;
            }
        }
    }
#pragma unroll
    for (int i = 0; i < 4; ++i) {
        size_t row = m0 + 4 * tm + i;
        float4 v0 = make_float4(acc[i][0], acc[i][1], acc[i][2], acc[i][3]);
        float4 v1 = make_float4(acc[i][4], acc[i][5], acc[i][6], acc[i][7]);
        *(float4*)(Cc + row * ldc + n0 + 4 * tn) = v0;
        *(float4*)(Cc + row * ldc + n0 + 64 + 4 * tn) = v1;
    }
}

// ---------------------------------------------------------------------------
// Attention: one wave per b; + copy slice in extra blocks
// ---------------------------------------------------------------------------
__global__ __launch_bounds__(64) void attn_kernel(
    const float* __restrict__ C, const float* __restrict__ memory,
    const int* __restrict__ gidx, const float* __restrict__ b_ih,
    const float* __restrict__ b_hh, float* __restrict__ mixq,
    float* __restrict__ ug, float* __restrict__ sg,
    const f32x4* __restrict__ src, f32x4* __restrict__ dst, size_t lo, size_t hi) {
    int bid = blockIdx.x;
    int t = threadIdx.x;
    if (bid >= B_) {
        size_t ctid = (size_t)(bid - B_) * 64 + t;
        copy_span(src, dst, lo, hi, ctid, (size_t)(gridDim.x - B_) * 64);
        return;
    }
    int b = bid;
    int t1 = t + 64;
    const float* Crow = C + (size_t)b * NC;
    float r0 = sigmf(Crow[t]        + b_ih[t]        + b_hh[t]);
    float r1 = sigmf(Crow[t1]       + b_ih[t1]       + b_hh[t1]);
    float u0 = sigmf(Crow[128 + t]  + b_ih[128 + t]  + b_hh[128 + t]);
    float u1 = sigmf(Crow[128 + t1] + b_ih[128 + t1] + b_hh[128 + t1]);
    float s0 = sigmf(Crow[256 + t]  + b_ih[384 + t]  + b_hh[384 + t]);
    float s1 = sigmf(Crow[256 + t1] + b_ih[384 + t1] + b_hh[384 + t1]);
    float n0 = tanhf(Crow[384 + t]  + b_ih[256 + t]  + r0 * (Crow[512 + t]  + b_hh[256 + t]));
    float n1 = tanhf(Crow[384 + t1] + b_ih[256 + t1] + r1 * (Crow[512 + t1] + b_hh[256 + t1]));

    int gx = gidx[2 * b] + 2, gy = gidx[2 * b + 1] + 2;
    const float* base = memory + ((size_t)gx * NW + gy) * H_ + t;
    float cs0[25], cs1[25];
#pragma unroll
    for (int l = 0; l < 25; ++l) {
        int dx = l / 5 - 2, dy = l % 5 - 2;
        const float* row = base + ((long)dx * NW + dy) * H_;
        cs0[l] = row[0];
        cs1[l] = row[64];
    }
    float sc[25];
#pragma unroll
    for (int l = 0; l < 25; ++l) {
        float p = n0 * cs0[l] + n1 * cs1[l];
#pragma unroll
        for (int w = 1; w < 64; w <<= 1) p += __shfl_xor(p, w, 64);
        sc[l] = p;
    }
    float mx = sc[0];
#pragma unroll
    for (int l = 1; l < 25; ++l) mx = fmaxf(mx, sc[l]);
    float den = 0.0f, mix0 = 0.0f, mix1 = 0.0f;
#pragma unroll
    for (int l = 0; l < 25; ++l) {
        float e = expf(sc[l] - mx);
        den += e;
        mix0 += e * cs0[l];
        mix1 += e * cs1[l];
    }
    float inv = 1.0f / den;
    mix0 *= inv; mix1 *= inv;

    float* mq = mixq + (size_t)b * 256;
    mq[t] = mix0; mq[t1] = mix1; mq[128 + t] = n0; mq[128 + t1] = n1;
    ug[(size_t)b * H_ + t] = u0; ug[(size_t)b * H_ + t1] = u1;
    sg[(size_t)b * H_ + t] = s0; sg[(size_t)b * H_ + t1] = s1;
}

// ---------------------------------------------------------------------------
// Pure bulk copy (serial-fallback path only)
// ---------------------------------------------------------------------------
__global__ void copy_kernel(const f32x4* __restrict__ src, f32x4* __restrict__ dst, size_t n4) {
    size_t stride = (size_t)gridDim.x * blockDim.x;
    for (size_t i = (size_t)blockIdx.x * blockDim.x + threadIdx.x; i < n4; i += stride) {
        f32x4 v = __builtin_nontemporal_load(src + i);
        __builtin_nontemporal_store(v, dst + i);
    }
}

// ---------------------------------------------------------------------------
// Final: hyy + scatter winner rows; + copy slice E skipping winner cells
// ---------------------------------------------------------------------------
__global__ __launch_bounds__(256) void final_kernel(
    const float* __restrict__ AC, const float* __restrict__ b_out,
    const float* __restrict__ sg, const float* __restrict__ ug,
    const float* __restrict__ mixq, const float* __restrict__ hx,
    const float* __restrict__ memory, const int* __restrict__ gidx,
    const int* __restrict__ winner, float* __restrict__ hyy,
    float* __restrict__ newmem,
    const f32x4* __restrict__ src, f32x4* __restrict__ dst, size_t lo, size_t hi) {
    size_t gt = (size_t)blockIdx.x * blockDim.x + threadIdx.x;
    size_t nthr = (size_t)gridDim.x * blockDim.x;
    for (size_t i = gt; i < (size_t)B_ * H_; i += nthr) {
        int b = (int)(i >> 7), t = (int)(i & 127);
        float atten = tanhf(AC[i] + b_out[t]);
        float s = sg[i], u = ug[i];
        float q = mixq[(size_t)b * 256 + 128 + t];
        float curr = q + s * atten;
        float hy = curr + u * (hx[i] - curr);
        hyy[i] = hy;
        int gx = gidx[2 * b] + 2, gy = gidx[2 * b + 1] + 2;
        size_t cell = (size_t)gx * NW + gy;
        if (winner[cell] == b) {
            float m = memory[cell * H_ + t];
            newmem[cell * H_ + t] = s * m + (1.0f - s) * hy;
        }
    }
    // copy slice, skipping cells owned by the scatter (written above)
    for (size_t i = lo + gt; i < hi; i += nthr) {
        if (winner[i >> 5] < 0) {
            f32x4 v = __builtin_nontemporal_load(src + i);
            __builtin_nontemporal_store(v, dst + i);
        }
    }
}

extern "C" void kernel_launch(void* const* d_in, const int* in_sizes, int n_in,
                              void* d_out, int out_size, void* d_ws, size_t ws_size,
                              hipStream_t stream) {
    const float* xf     = (const float*)d_in[0];
    const float* hx     = (const float*)d_in[1];
    const int*   gidx   = (const int*)d_in[2];
    const float* memory = (const float*)d_in[3];
    const float* w_ih   = (const float*)d_in[4];
    const float* w_hh   = (const float*)d_in[5];
    const float* b_ih   = (const float*)d_in[6];
    const float* b_hh   = (const float*)d_in[7];
    const float* w_out  = (const float*)d_in[8];
    const float* b_out  = (const float*)d_in[9];

    float* out    = (float*)d_out;
    float* hyy    = out;
    float* newmem = out + (size_t)B_ * H_;
    const f32x4* src4 = (const f32x4*)memory;
    f32x4*       dst4 = (f32x4*)newmem;

    // Persistent scratch: mixq, ug, sg, AC, winner
    float* wsf    = (float*)d_ws;
    float* mixq   = wsf;                        // B*256
    float* ug     = mixq + (size_t)B_ * 256;    // B*128
    float* sg     = ug + (size_t)B_ * H_;       // B*128
    float* AC     = sg + (size_t)B_ * H_;       // B*128
    int*   winner = (int*)(AC + (size_t)B_ * H_);   // NW*NW ints
    char*  pers_end = (char*)(winner + (size_t)NW * NW);
    size_t pers_bytes = (size_t)(pers_end - (char*)d_ws);

    size_t ZF = (size_t)B_ * 256, CF = (size_t)B_ * NC, WBF = (size_t)NC * 256;
    size_t trans_bytes = (ZF + CF + WBF) * sizeof(float);
    bool distributed = (ws_size >= pers_bytes + trans_bytes);
    float* trans = distributed ? (float*)pers_end : newmem;
    float* Z    = trans;
    float* Cbuf = Z + ZF;
    float* Wbig = Cbuf + CF;

    if (distributed) {
        size_t a1 = SL_A, b1 = a1 + SL_B, c1 = b1 + SL_C, d1 = c1 + SL_D;
        prep_kernel<<<PREP_CB + PREP_CPB, 256, 0, stream>>>(
            xf, hx, w_ih, w_hh, Z, Wbig, winner, src4, dst4, 0, a1);
        gemm_abt<<<640 + GEMM_CPB, 256, 0, stream>>>(
            Z, Wbig, Cbuf, NC, 128, 640, gidx, winner, src4, dst4, a1, b1);
        attn_kernel<<<B_ + ATTN_CPB, 64, 0, stream>>>(
            Cbuf, memory, gidx, b_ih, b_hh, mixq, ug, sg, src4, dst4, b1, c1);
        gemm_abt<<<128 + GEMM_CPB, 256, 0, stream>>>(
            mixq, w_out, AC, H_, 128, 128, nullptr, winner, src4, dst4, c1, d1);
        final_kernel<<<FIN_BLKS, 256, 0, stream>>>(
            AC, b_out, sg, ug, mixq, hx, memory, gidx, winner, hyy, newmem,
            src4, dst4, d1, N4TOT);
    } else {
        // serial fallback: transients staged in not-yet-copied newmem region
        prep_kernel<<<PREP_CB, 256, 0, stream>>>(
            xf, hx, w_ih, w_hh, Z, Wbig, winner, src4, dst4, 0, 0);
        gemm_abt<<<640 + 32, 256, 0, stream>>>(
            Z, Wbig, Cbuf, NC, 128, 640, gidx, winner, src4, dst4, 0, 0);
        attn_kernel<<<B_, 64, 0, stream>>>(
            Cbuf, memory, gidx, b_ih, b_hh, mixq, ug, sg, src4, dst4, 0, 0);
        gemm_abt<<<128, 256, 0, stream>>>(
            mixq, w_out, AC, H_, 128, 128, nullptr, winner, src4, dst4, 0, 0);
        copy_kernel<<<2048, 256, 0, stream>>>(src4, dst4, N4TOT);
        final_kernel<<<FIN_BLKS, 256, 0, stream>>>(
            AC, b_out, sg, ug, mixq, hx, memory, gidx, winner, hyy, newmem,
            src4, dst4, 0, 0);
    }
}